// Round 13
// baseline (64.489 us; speedup 1.0000x reference)
//
#include <hip/hip_runtime.h>
#include <hip/hip_bf16.h>

#define B_ 32
#define T_ 256
#define NIN_ 128
#define H_ 32
#define NOUT_ 128
#define R_ (B_ * T_)   // 8192 rows

#define C2L2E 2.88539008177792681472f   // 2*log2(e)
#define L2E   1.44269504088896341f
#define LN2   0.69314718055994531f

__device__ __forceinline__ float rcpf(float x) { return __builtin_amdgcn_rcpf(x); }

// ---------------------------------------------------------------------------
// Kernel 1 (fused, r10-proven): per block = 8 rows x 32 h (256 threads).
//   y = x @ W_in^T + b_in ; Eh = exp2(c*y@W_h^T) ; Eo = exp2(c*y@W_o^T)
// ---------------------------------------------------------------------------
__global__ void __launch_bounds__(256) k_yho(
        const float* __restrict__ x,
        const float* __restrict__ W_in,
        const float* __restrict__ b_in,
        const float* __restrict__ W_h,
        const float* __restrict__ W_o,
        float* __restrict__ y,
        float* __restrict__ Eh,
        float* __restrict__ Eo) {
    __shared__ float xs[8][NIN_];   // 4 KB
    __shared__ float ys[8][H_];     // 1 KB
    const int t   = threadIdx.x;
    const int r   = t >> 5;              // local row 0..7
    const int hh  = t & 31;
    const int row = blockIdx.x * 8 + r;
    const int idx = row * H_ + hh;

    reinterpret_cast<float4*>(&xs[0][0])[t] =
        reinterpret_cast<const float4*>(x + (blockIdx.x * 8) * NIN_)[t];
    __syncthreads();

    {
        const float4* xl = reinterpret_cast<const float4*>(&xs[r][0]);
        const float4* w4 = reinterpret_cast<const float4*>(W_in + hh * NIN_);
        float a0 = b_in[hh], a1 = 0.f;
        #pragma unroll
        for (int k = 0; k < NIN_ / 8; ++k) {
            float4 xv0 = xl[2 * k],     wv0 = w4[2 * k];
            float4 xv1 = xl[2 * k + 1], wv1 = w4[2 * k + 1];
            a0 += xv0.x * wv0.x + xv0.y * wv0.y + xv0.z * wv0.z + xv0.w * wv0.w;
            a1 += xv1.x * wv1.x + xv1.y * wv1.y + xv1.z * wv1.z + xv1.w * wv1.w;
        }
        float acc = a0 + a1;
        ys[r][hh] = acc;
        y[idx] = acc;
    }
    __syncthreads();

    {
        const float4* y4  = reinterpret_cast<const float4*>(&ys[r][0]);
        const float4* wh4 = reinterpret_cast<const float4*>(W_h + hh * H_);
        const float4* wo4 = reinterpret_cast<const float4*>(W_o + hh * H_);
        float ah0 = 0.f, ah1 = 0.f, ao0 = 0.f, ao1 = 0.f;
        #pragma unroll
        for (int k = 0; k < H_ / 8; ++k) {
            float4 yv0 = y4[2 * k],     hv0 = wh4[2 * k],     ov0 = wo4[2 * k];
            float4 yv1 = y4[2 * k + 1], hv1 = wh4[2 * k + 1], ov1 = wo4[2 * k + 1];
            ah0 += yv0.x * hv0.x + yv0.y * hv0.y + yv0.z * hv0.z + yv0.w * hv0.w;
            ah1 += yv1.x * hv1.x + yv1.y * hv1.y + yv1.z * hv1.z + yv1.w * hv1.w;
            ao0 += yv0.x * ov0.x + yv0.y * ov0.y + yv0.z * ov0.z + yv0.w * ov0.w;
            ao1 += yv1.x * ov1.x + yv1.y * ov1.y + yv1.z * ov1.z + yv1.w * ov1.w;
        }
        Eh[idx] = __builtin_amdgcn_exp2f((ah0 + ah1) * C2L2E);
        Eo[idx] = __builtin_amdgcn_exp2f((ao0 + ao1) * C2L2E);
    }
}

// ---------------------------------------------------------------------------
// Kernel 2: score + log-softmax -> att (global, 8MB).
// block = 256 thd = 4 waves = 4 j-slices; block owns 8 queries of batch bb.
// Lane owns j: Eo_j in 32 VGPRs, loaded ONCE, reused across 8 queries.
// Eh rows broadcast from 1KB LDS stage. k-reduction fully IN-LANE (no shfl
// in the k-loop; r12 lesson). exp + butterfly AFTER the compute loop.
// Fixed-shift softmax (|E| <= va = sum|V|), r12-proven numerics.
// ---------------------------------------------------------------------------
__global__ void __launch_bounds__(256) k_score(
        const float* __restrict__ Eh,
        const float* __restrict__ Eo,
        const float* __restrict__ V,
        float* __restrict__ att) {
    __shared__ float ehs[8 * H_];    // 1 KB
    __shared__ float sred[4][8];     // 128 B

    const int t    = threadIdx.x;
    const int w    = __builtin_amdgcn_readfirstlane(t >> 6);  // j-slice 0..3
    const int lane = t & 63;
    const int bb   = blockIdx.x >> 5;           // batch
    const int qb   = (blockIdx.x & 31) << 3;    // query octet base
    const int rbase = bb * T_ + qb;

    // ---- stage 8 Eh rows (contiguous 1KB) ----
    if (t < 64)
        reinterpret_cast<float4*>(ehs)[t] =
            reinterpret_cast<const float4*>(Eh + rbase * H_)[t];

    // ---- w2 = -2V, vs = sum V, va = sum |V| (per-lane, broadcast loads) ----
    float w2[H_];
    float vs = 0.f, va = 0.f;
    {
        const float4* vp = reinterpret_cast<const float4*>(V);
        #pragma unroll
        for (int p = 0; p < 8; ++p) {
            float4 v = vp[p];
            w2[4 * p + 0] = v.x * -2.f; w2[4 * p + 1] = v.y * -2.f;
            w2[4 * p + 2] = v.z * -2.f; w2[4 * p + 3] = v.w * -2.f;
            vs += (v.x + v.y) + (v.z + v.w);
            va += (fabsf(v.x) + fabsf(v.y)) + (fabsf(v.z) + fabsf(v.w));
        }
    }
    __syncthreads();

    // ---- Eo row for this lane's j: 32 VGPRs, loaded once ----
    const int j = (w << 6) + lane;
    float4 eo[8];
    {
        const float4* ep = reinterpret_cast<const float4*>(Eo + (bb * T_ + j) * H_);
        #pragma unroll
        for (int p = 0; p < 8; ++p) eo[p] = ep[p];
    }

    // ---- E for 8 queries, all in-lane ----
    float E[8];
    #pragma unroll
    for (int q = 0; q < 8; ++q) {
        const float4* ehq = reinterpret_cast<const float4*>(ehs + q * H_);
        float a0 = 0.f, a1 = 0.f, a2 = 0.f, a3 = 0.f;
        #pragma unroll
        for (int p = 0; p < 8; ++p) {
            float4 e4 = ehq[p];     // wave-uniform LDS broadcast
            a0 = fmaf(w2[4 * p + 0], rcpf(fmaf(e4.x, eo[p].x, 1.f)), a0);
            a1 = fmaf(w2[4 * p + 1], rcpf(fmaf(e4.y, eo[p].y, 1.f)), a1);
            a2 = fmaf(w2[4 * p + 2], rcpf(fmaf(e4.z, eo[p].z, 1.f)), a2);
            a3 = fmaf(w2[4 * p + 3], rcpf(fmaf(e4.w, eo[p].w, 1.f)), a3);
        }
        E[q] = ((a0 + a1) + (a2 + a3)) + vs;
    }

    // ---- exp (fixed shift) + butterfly s-reduction, outside the k-loop ----
    const float soff = -va * L2E;
    float s[8];
    #pragma unroll
    for (int q = 0; q < 8; ++q)
        s[q] = __builtin_amdgcn_exp2f(fmaf(E[q], L2E, soff));
    #pragma unroll
    for (int off = 1; off < 64; off <<= 1) {
        #pragma unroll
        for (int q = 0; q < 8; ++q)
            s[q] += __shfl_xor(s[q], off);
    }
    if (lane == 0) {
        float4 sa, sb;
        sa.x = s[0]; sa.y = s[1]; sa.z = s[2]; sa.w = s[3];
        sb.x = s[4]; sb.y = s[5]; sb.z = s[6]; sb.w = s[7];
        *reinterpret_cast<float4*>(&sred[w][0]) = sa;
        *reinterpret_cast<float4*>(&sred[w][4]) = sb;
    }
    __syncthreads();

    // ---- lse per query, write att rows (coalesced 256B per wave) ----
    #pragma unroll
    for (int q = 0; q < 8; ++q) {
        float st = (sred[0][q] + sred[1][q]) + (sred[2][q] + sred[3][q]);
        float lse = va + __builtin_amdgcn_logf(st) * LN2;
        att[(rbase + q) * T_ + j] = E[q] - lse;
    }
}

// ---------------------------------------------------------------------------
// Kernel 3: ctx = att @ y  (per batch [256x256]x[256x32]) + out-projection.
// block = 256 thd = 4 waves; block owns 8 queries. att staged in LDS
// (stride-264 rows -> js-groups hit distinct banks). y read GLOBAL, fully
// coalesced: lane=(hq,js), j=n*8+js -> each instr covers 1KB contiguous.
// ctx accum in-lane (4-wide), 3-stage shfl epilogue; out-proj wave-local.
// ---------------------------------------------------------------------------
__global__ void __launch_bounds__(256) k_ctxout(
        const float* __restrict__ att,
        const float* __restrict__ y,
        const float* __restrict__ W_out,
        const float* __restrict__ b_out,
        float* __restrict__ out) {
    __shared__ float att_s[8][264];   // 8.25 KB
    __shared__ float ctx_s[8][H_];    // 1 KB

    const int t    = threadIdx.x;
    const int w    = __builtin_amdgcn_readfirstlane(t >> 6);
    const int lane = t & 63;
    const int bb   = blockIdx.x >> 5;
    const int qb   = (blockIdx.x & 31) << 3;
    const int rbase = bb * T_ + qb;

    // ---- stage 8 att rows (2 float4 per thread, coalesced) ----
    {
        const float4* ag = reinterpret_cast<const float4*>(att + rbase * T_);
        #pragma unroll
        for (int rr = 0; rr < 2; ++rr) {
            const int idx = rr * 256 + t;          // 0..511
            const int q  = idx >> 6;
            const int jj = (idx & 63) << 2;
            *reinterpret_cast<float4*>(&att_s[q][jj]) = ag[idx];
        }
    }
    __syncthreads();

    // ---- ctx: wave w handles queries q0=2w, q1=2w+1 ----
    const int hq = lane & 7;       // h-quad
    const int js = lane >> 3;      // j-interleave slot
    const int q0 = 2 * w, q1 = q0 + 1;
    float4 c0 = {0, 0, 0, 0}, c1 = {0, 0, 0, 0};
    {
        const float4* yb = reinterpret_cast<const float4*>(
            y + (bb * T_ + js) * H_ + hq * 4);
        #pragma unroll
        for (int n = 0; n < 32; ++n) {
            const int jj = n * 8 + js;
            float4 yv = yb[n * 8 * (H_ / 4)];      // global, coalesced
            float a0 = att_s[q0][jj];
            float a1 = att_s[q1][jj];
            c0.x = fmaf(a0, yv.x, c0.x); c0.y = fmaf(a0, yv.y, c0.y);
            c0.z = fmaf(a0, yv.z, c0.z); c0.w = fmaf(a0, yv.w, c0.w);
            c1.x = fmaf(a1, yv.x, c1.x); c1.y = fmaf(a1, yv.y, c1.y);
            c1.z = fmaf(a1, yv.z, c1.z); c1.w = fmaf(a1, yv.w, c1.w);
        }
    }
    #pragma unroll
    for (int off = 8; off < 64; off <<= 1) {
        c0.x += __shfl_xor(c0.x, off); c0.y += __shfl_xor(c0.y, off);
        c0.z += __shfl_xor(c0.z, off); c0.w += __shfl_xor(c0.w, off);
        c1.x += __shfl_xor(c1.x, off); c1.y += __shfl_xor(c1.y, off);
        c1.z += __shfl_xor(c1.z, off); c1.w += __shfl_xor(c1.w, off);
    }
    if (js == 0) {
        *reinterpret_cast<float4*>(&ctx_s[q0][hq * 4]) = c0;
        *reinterpret_cast<float4*>(&ctx_s[q1][hq * 4]) = c1;
    }
    // ctx_s written and read by the SAME wave (oq = t>>5 in {2w, 2w+1})
    // -> same-wave LDS ordering via lgkmcnt, no barrier needed.

    // ---- out-projection: thread = (oq = t>>5, ol = t&31), 4 oc each ----
    {
        const int oq = t >> 5;
        const int ol = t & 31;
        float4 cv[8];
        #pragma unroll
        for (int p = 0; p < 8; ++p)
            cv[p] = *reinterpret_cast<const float4*>(&ctx_s[oq][4 * p]);
        float* orow = out + (rbase + oq) * NOUT_;
        #pragma unroll
        for (int u = 0; u < 4; ++u) {
            const int oc = ol + 32 * u;
            const float4* wp = reinterpret_cast<const float4*>(W_out + oc * H_);
            float p0 = b_out[oc], p1 = 0.f, p2 = 0.f, p3 = 0.f;
            #pragma unroll
            for (int p = 0; p < 8; p += 4) {
                float4 w0 = wp[p], w1 = wp[p + 1], w2 = wp[p + 2], w3 = wp[p + 3];
                p0 += w0.x * cv[p].x + w0.y * cv[p].y + w0.z * cv[p].z + w0.w * cv[p].w;
                p1 += w1.x * cv[p+1].x + w1.y * cv[p+1].y + w1.z * cv[p+1].z + w1.w * cv[p+1].w;
                p2 += w2.x * cv[p+2].x + w2.y * cv[p+2].y + w2.z * cv[p+2].z + w2.w * cv[p+2].w;
                p3 += w3.x * cv[p+3].x + w3.y * cv[p+3].y + w3.z * cv[p+3].z + w3.w * cv[p+3].w;
            }
            orow[oc] = (p0 + p1) + (p2 + p3);
        }
    }
}

// ---------------------------------------------------------------------------
extern "C" void kernel_launch(void* const* d_in, const int* in_sizes, int n_in,
                              void* d_out, int out_size, void* d_ws, size_t ws_size,
                              hipStream_t stream) {
    const float* x     = (const float*)d_in[0];
    const float* W_in  = (const float*)d_in[1];
    const float* b_in  = (const float*)d_in[2];
    const float* W_h   = (const float*)d_in[3];
    const float* W_o   = (const float*)d_in[4];
    const float* V     = (const float*)d_in[5];
    const float* W_out = (const float*)d_in[6];
    const float* b_out = (const float*)d_in[7];
    float* out = (float*)d_out;

    // workspace: y | Eh | Eo (1MB each) | att (8MB)
    float* y   = (float*)d_ws;
    float* Eh  = y + R_ * H_;
    float* Eo  = Eh + R_ * H_;
    float* att = Eo + R_ * H_;

    k_yho   <<<R_ / 8, 256, 0, stream>>>(x, W_in, b_in, W_h, W_o, y, Eh, Eo);
    k_score <<<R_ / 8, 256, 0, stream>>>(Eh, Eo, V, att);
    k_ctxout<<<R_ / 8, 256, 0, stream>>>(att, y, W_out, b_out, out);
}

// Round 14
// 48.169 us; speedup vs baseline: 1.3388x; 1.3388x over previous
//
#include <hip/hip_runtime.h>
#include <hip/hip_bf16.h>

#define B_ 32
#define T_ 256
#define NIN_ 128
#define H_ 32
#define NOUT_ 128
#define R_ (B_ * T_)   // 8192 rows

#define C2L2E 2.88539008177792681472f   // 2*log2(e)
#define L2E   1.44269504088896341f
#define LN2   0.69314718055994531f

__device__ __forceinline__ float rfl(float x) {
    return __uint_as_float(__builtin_amdgcn_readfirstlane(__float_as_uint(x)));
}
__device__ __forceinline__ float rcpf(float x) { return __builtin_amdgcn_rcpf(x); }

// ---------------------------------------------------------------------------
// Kernel 1 (fused, r10-proven ~5us): per block = 8 rows x 32 h (256 threads).
// x rows staged cooperatively in LDS (one float4 load/thread).
//   y = x @ W_in^T + b_in ; Eh = exp2(c*y@W_h^T) ; Eo = exp2(c*y@W_o^T)
// ---------------------------------------------------------------------------
__global__ void __launch_bounds__(256) k_yho(
        const float* __restrict__ x,
        const float* __restrict__ W_in,
        const float* __restrict__ b_in,
        const float* __restrict__ W_h,
        const float* __restrict__ W_o,
        float* __restrict__ y,
        float* __restrict__ Eh,
        float* __restrict__ Eo) {
    __shared__ float xs[8][NIN_];   // 4 KB
    __shared__ float ys[8][H_];     // 1 KB
    const int t   = threadIdx.x;
    const int r   = t >> 5;              // local row 0..7
    const int hh  = t & 31;
    const int row = blockIdx.x * 8 + r;
    const int idx = row * H_ + hh;

    reinterpret_cast<float4*>(&xs[0][0])[t] =
        reinterpret_cast<const float4*>(x + (blockIdx.x * 8) * NIN_)[t];
    __syncthreads();

    {
        const float4* xl = reinterpret_cast<const float4*>(&xs[r][0]);
        const float4* w4 = reinterpret_cast<const float4*>(W_in + hh * NIN_);
        float a0 = b_in[hh], a1 = 0.f;
        #pragma unroll
        for (int k = 0; k < NIN_ / 8; ++k) {
            float4 xv0 = xl[2 * k],     wv0 = w4[2 * k];
            float4 xv1 = xl[2 * k + 1], wv1 = w4[2 * k + 1];
            a0 += xv0.x * wv0.x + xv0.y * wv0.y + xv0.z * wv0.z + xv0.w * wv0.w;
            a1 += xv1.x * wv1.x + xv1.y * wv1.y + xv1.z * wv1.z + xv1.w * wv1.w;
        }
        float acc = a0 + a1;
        ys[r][hh] = acc;
        y[idx] = acc;
    }
    __syncthreads();

    {
        const float4* y4  = reinterpret_cast<const float4*>(&ys[r][0]);
        const float4* wh4 = reinterpret_cast<const float4*>(W_h + hh * H_);
        const float4* wo4 = reinterpret_cast<const float4*>(W_o + hh * H_);
        float ah0 = 0.f, ah1 = 0.f, ao0 = 0.f, ao1 = 0.f;
        #pragma unroll
        for (int k = 0; k < H_ / 8; ++k) {
            float4 yv0 = y4[2 * k],     hv0 = wh4[2 * k],     ov0 = wo4[2 * k];
            float4 yv1 = y4[2 * k + 1], hv1 = wh4[2 * k + 1], ov1 = wo4[2 * k + 1];
            ah0 += yv0.x * hv0.x + yv0.y * hv0.y + yv0.z * hv0.z + yv0.w * hv0.w;
            ah1 += yv1.x * hv1.x + yv1.y * hv1.y + yv1.z * hv1.z + yv1.w * hv1.w;
            ao0 += yv0.x * ov0.x + yv0.y * ov0.y + yv0.z * ov0.z + yv0.w * ov0.w;
            ao1 += yv1.x * ov1.x + yv1.y * ov1.y + yv1.z * ov1.z + yv1.w * ov1.w;
        }
        Eh[idx] = __builtin_amdgcn_exp2f((ah0 + ah1) * C2L2E);
        Eo[idx] = __builtin_amdgcn_exp2f((ao0 + ao1) * C2L2E);
    }
}

// ---------------------------------------------------------------------------
// Kernel 2 (r10 structure + overlap/coalescing fixes):
// block = 8 waves = 16 queries of one batch bb (512 threads), (512,4) bound.
// FIX 1: Eh-row loads issued BEFORE the staging loop (fly under staging+bar).
// FIX 2: ctx phase j = n*8+js -> each wave y-load = 1KB contiguous; att in
//        PLAIN layout (writes coalesced, reads 8-lane broadcast, no conflict).
// ---------------------------------------------------------------------------
__global__ void __launch_bounds__(512, 4) k_att(
        const float* __restrict__ y,
        const float* __restrict__ Eh,
        const float* __restrict__ Eo,
        const float* __restrict__ V,
        const float* __restrict__ W_out,
        const float* __restrict__ b_out,
        float* __restrict__ out) {
    __shared__ float eo_swz[T_ * H_];      // 32 KB
    __shared__ float att_p[8][2][T_];      // 16 KB, PLAIN layout
    __shared__ float ctx_lds[8][2][H_];    // 2 KB

    const int t    = threadIdx.x;
    const int w    = __builtin_amdgcn_readfirstlane(t >> 6);  // wave 0..7
    const int lane = t & 63;
    const int r0   = blockIdx.x * 16 + 2 * w;   // query rows r0, r0+1
    const int r1   = r0 + 1;
    const int bb   = blockIdx.x >> 4;           // batch (16 queries/block)

    // ---- FIX 1: issue wave-uniform Eh-row loads FIRST ----
    float4 ha[8], hb[8];
    {
        const float4* h04 = reinterpret_cast<const float4*>(Eh + r0 * H_);
        const float4* h14 = reinterpret_cast<const float4*>(Eh + r1 * H_);
        #pragma unroll
        for (int p = 0; p < 8; ++p) { ha[p] = h04[p]; hb[p] = h14[p]; }
    }

    // ---- stage Eo tile (swizzled), all 512 threads ----
    {
        const float4* eg = reinterpret_cast<const float4*>(Eo + bb * T_ * H_);
        float4 tmp[4];
        #pragma unroll
        for (int n = 0; n < 4; ++n) tmp[n] = eg[n * 512 + t];
        #pragma unroll
        for (int n = 0; n < 4; ++n) {
            int c = n * 512 + t;
            int j = c >> 3, p = c & 7;
            *reinterpret_cast<float4*>(&eo_swz[j * H_ + (((p ^ j) & 7) << 2)]) = tmp[n];
        }
    }
    __syncthreads();

    // ---- convert preamble: eh0 -> SGPR, eh1 = hb (VGPR); w2/vsum -> SGPR ----
    float eh0[H_];   // rfl'd -> SGPR
    float eh1[H_];   // VGPR
    float w2[H_];    // rfl'd -> SGPR
    float vsum = 0.f;
    {
        #pragma unroll
        for (int p = 0; p < 8; ++p) {
            eh0[4 * p + 0] = rfl(ha[p].x); eh0[4 * p + 1] = rfl(ha[p].y);
            eh0[4 * p + 2] = rfl(ha[p].z); eh0[4 * p + 3] = rfl(ha[p].w);
            eh1[4 * p + 0] = hb[p].x; eh1[4 * p + 1] = hb[p].y;
            eh1[4 * p + 2] = hb[p].z; eh1[4 * p + 3] = hb[p].w;
        }
        const float4* V4 = reinterpret_cast<const float4*>(V);
        #pragma unroll
        for (int p = 0; p < 8; ++p) {
            float4 v = V4[p];
            w2[4 * p + 0] = rfl(v.x * -2.0f); w2[4 * p + 1] = rfl(v.y * -2.0f);
            w2[4 * p + 2] = rfl(v.z * -2.0f); w2[4 * p + 3] = rfl(v.w * -2.0f);
            vsum += (v.x + v.y) + (v.z + v.w);
        }
        vsum = rfl(vsum);
    }

    // ---- e for 4 j's per lane, both queries; Eo rows from LDS ----
    float E0[4], E1[4];
    #pragma unroll
    for (int q = 0; q < 4; ++q) {
        const int j  = lane + 64 * q;
        const int jb = j * H_;
        const int jx = (j & 7) << 2;
        float4 ev[8];
        #pragma unroll
        for (int p = 0; p < 8; ++p)
            ev[p] = *reinterpret_cast<const float4*>(&eo_swz[jb + ((p << 2) ^ jx)]);
        float a00 = 0.f, a01 = 0.f, a02 = 0.f, a03 = 0.f;
        float a10 = 0.f, a11 = 0.f, a12 = 0.f, a13 = 0.f;
        #pragma unroll
        for (int p = 0; p < 8; ++p) {
            const int k = 4 * p;
            float d;
            d = fmaf(eh0[k + 0], ev[p].x, 1.0f);
            a00 = fmaf(w2[k + 0], rcpf(d), a00);
            d = fmaf(eh1[k + 0], ev[p].x, 1.0f);
            a10 = fmaf(w2[k + 0], rcpf(d), a10);
            d = fmaf(eh0[k + 1], ev[p].y, 1.0f);
            a01 = fmaf(w2[k + 1], rcpf(d), a01);
            d = fmaf(eh1[k + 1], ev[p].y, 1.0f);
            a11 = fmaf(w2[k + 1], rcpf(d), a11);
            d = fmaf(eh0[k + 2], ev[p].z, 1.0f);
            a02 = fmaf(w2[k + 2], rcpf(d), a02);
            d = fmaf(eh1[k + 2], ev[p].z, 1.0f);
            a12 = fmaf(w2[k + 2], rcpf(d), a12);
            d = fmaf(eh0[k + 3], ev[p].w, 1.0f);
            a03 = fmaf(w2[k + 3], rcpf(d), a03);
            d = fmaf(eh1[k + 3], ev[p].w, 1.0f);
            a13 = fmaf(w2[k + 3], rcpf(d), a13);
        }
        E0[q] = ((a00 + a01) + (a02 + a03)) + vsum;
        E1[q] = ((a10 + a11) + (a12 + a13)) + vsum;
    }

    // ---- wave-local softmax (no barriers), per query ----
    float m0 = fmaxf(fmaxf(E0[0], E0[1]), fmaxf(E0[2], E0[3]));
    float m1 = fmaxf(fmaxf(E1[0], E1[1]), fmaxf(E1[2], E1[3]));
    #pragma unroll
    for (int off = 1; off < 64; off <<= 1) {
        m0 = fmaxf(m0, __shfl_xor(m0, off));
        m1 = fmaxf(m1, __shfl_xor(m1, off));
    }
    float s0 = 0.f, s1 = 0.f;
    #pragma unroll
    for (int q = 0; q < 4; ++q) {
        s0 += __builtin_amdgcn_exp2f((E0[q] - m0) * L2E);
        s1 += __builtin_amdgcn_exp2f((E1[q] - m1) * L2E);
    }
    #pragma unroll
    for (int off = 1; off < 64; off <<= 1) {
        s0 += __shfl_xor(s0, off);
        s1 += __shfl_xor(s1, off);
    }
    const float lse0 = m0 + __builtin_amdgcn_logf(s0) * LN2;
    const float lse1 = m1 + __builtin_amdgcn_logf(s1) * LN2;

    // ---- FIX 2a: PLAIN att store (consecutive lanes -> consecutive addr) ----
    #pragma unroll
    for (int q = 0; q < 4; ++q) {
        const int j = lane + 64 * q;
        att_p[w][0][j] = E0[q] - lse0;
        att_p[w][1][j] = E1[q] - lse1;
    }
    // same-wave LDS produce->consume: ordered by lgkmcnt, no barrier needed

    // ---- FIX 2b: ctx with coalesced y: lane=(hq 0..7, js 0..7), j=n*8+js ----
    {
        const int hq = lane & 7;
        const int js = lane >> 3;
        const float4* yb = reinterpret_cast<const float4*>(
            y + (bb * T_ + js) * H_ + hq * 4);
        float4 c0 = {0, 0, 0, 0}, c1 = {0, 0, 0, 0};
        #pragma unroll
        for (int n = 0; n < 32; ++n) {
            const int jj = n * 8 + js;
            float4 yv = yb[n * 8 * (H_ / 4)];      // wave covers 1KB contiguous
            float a0 = att_p[w][0][jj];            // 8-addr, 8-lane broadcast
            float a1 = att_p[w][1][jj];
            c0.x = fmaf(a0, yv.x, c0.x); c0.y = fmaf(a0, yv.y, c0.y);
            c0.z = fmaf(a0, yv.z, c0.z); c0.w = fmaf(a0, yv.w, c0.w);
            c1.x = fmaf(a1, yv.x, c1.x); c1.y = fmaf(a1, yv.y, c1.y);
            c1.z = fmaf(a1, yv.z, c1.z); c1.w = fmaf(a1, yv.w, c1.w);
        }
        // reduce over js axis (lane bits 3,4,5)
        #pragma unroll
        for (int off = 8; off < 64; off <<= 1) {
            c0.x += __shfl_xor(c0.x, off); c0.y += __shfl_xor(c0.y, off);
            c0.z += __shfl_xor(c0.z, off); c0.w += __shfl_xor(c0.w, off);
            c1.x += __shfl_xor(c1.x, off); c1.y += __shfl_xor(c1.y, off);
            c1.z += __shfl_xor(c1.z, off); c1.w += __shfl_xor(c1.w, off);
        }
        if (js == 0) {
            *reinterpret_cast<float4*>(&ctx_lds[w][0][4 * hq]) = c0;
            *reinterpret_cast<float4*>(&ctx_lds[w][1][4 * hq]) = c1;
        }
    }

    // ---- output projection: 2 channels/lane x 2 queries, W_out shared ----
    float4 cv0[8], cv1[8];
    #pragma unroll
    for (int p = 0; p < 8; ++p) {
        cv0[p] = *reinterpret_cast<const float4*>(&ctx_lds[w][0][4 * p]);
        cv1[p] = *reinterpret_cast<const float4*>(&ctx_lds[w][1][4 * p]);
    }
    #pragma unroll
    for (int ho = 0; ho < 2; ++ho) {
        const int oc = lane + 64 * ho;
        const float4* w4 = reinterpret_cast<const float4*>(W_out + oc * H_);
        float b  = b_out[oc];
        float p0 = 0.f, p0b = 0.f, p1 = 0.f, p1b = 0.f;
        #pragma unroll
        for (int p = 0; p < 8; p += 2) {
            float4 wv0 = w4[p], wv1 = w4[p + 1];
            p0  += wv0.x * cv0[p].x + wv0.y * cv0[p].y + wv0.z * cv0[p].z + wv0.w * cv0[p].w;
            p0b += wv1.x * cv0[p+1].x + wv1.y * cv0[p+1].y + wv1.z * cv0[p+1].z + wv1.w * cv0[p+1].w;
            p1  += wv0.x * cv1[p].x + wv0.y * cv1[p].y + wv0.z * cv1[p].z + wv0.w * cv1[p].w;
            p1b += wv1.x * cv1[p+1].x + wv1.y * cv1[p+1].y + wv1.z * cv1[p+1].z + wv1.w * cv1[p+1].w;
        }
        out[r0 * NOUT_ + oc] = b + p0 + p0b;
        out[r1 * NOUT_ + oc] = b + p1 + p1b;
    }
}

// ---------------------------------------------------------------------------
extern "C" void kernel_launch(void* const* d_in, const int* in_sizes, int n_in,
                              void* d_out, int out_size, void* d_ws, size_t ws_size,
                              hipStream_t stream) {
    const float* x     = (const float*)d_in[0];
    const float* W_in  = (const float*)d_in[1];
    const float* b_in  = (const float*)d_in[2];
    const float* W_h   = (const float*)d_in[3];
    const float* W_o   = (const float*)d_in[4];
    const float* V     = (const float*)d_in[5];
    const float* W_out = (const float*)d_in[6];
    const float* b_out = (const float*)d_in[7];
    float* out = (float*)d_out;

    // workspace layout: y | Eh | Eo  (each R_*H_ floats = 1 MB)
    float* y  = (float*)d_ws;
    float* Eh = y + R_ * H_;
    float* Eo = Eh + R_ * H_;

    k_yho<<<R_ / 8, 256, 0, stream>>>(x, W_in, b_in, W_h, W_o, y, Eh, Eo);
    k_att<<<R_ / 16, 512, 0, stream>>>(y, Eh, Eo, V, W_out, b_out, out);
}